// Round 14
// baseline (180.163 us; speedup 1.0000x reference)
//
#include <hip/hip_runtime.h>
#include <hip/hip_bf16.h>

// CellAnnotator R14 = R13 + two K1 refinements (K0/K2 byte-identical, proven):
//  1) Full 5-bit XOR swizzle pos = g ^ (row&31) (bijective over 32 groups/row):
//     X ds_write_b128 was 8-way bank-conflicted with the old 3-bit key (rows stride
//     512B == bank 0; lanes sharing lane&7 hit the same slot column). Now 2-way (free).
//  2) Interior fast path: tiles not touching an image edge (~96%) skip clamps/masks and
//     use one row base + immediate offsets for halo loads. Bit-exact on interior tiles.

#define HH 768
#define WW 768
#define HWPX (HH*WW)

typedef __attribute__((ext_vector_type(8))) short short8;
typedef __attribute__((ext_vector_type(8))) _Float16 half8;
typedef __attribute__((ext_vector_type(4))) float f32x4;
typedef __attribute__((ext_vector_type(16))) float f32x16;

union hcvt { _Float16 h; ushort u; };
__device__ __forceinline__ ushort f2h(float f) { hcvt c; c.h = (_Float16)f; return c.u; }
__device__ __forceinline__ float sigmoidf(float v) { return 1.f / (1.f + __expf(-v)); }

// K1 LDS: row pitch 256 ushorts (512B = 32 groups of 16B). Full 5-bit XOR swizzle.
__device__ __forceinline__ int goff(int row, int g) {
  return (row << 8) + ((g ^ (row & 31)) << 3);
}
__device__ __forceinline__ int eoff(int row, int k) {
  return (row << 8) + (((k >> 3) ^ (row & 31)) << 3) + (k & 7);
}

// ---------------- K0: fold params into weights (unchanged) ----------------
__global__ __launch_bounds__(256)
void prep_wf(const float* __restrict__ Ws, const float* __restrict__ bs,
             const float* __restrict__ lns, const float* __restrict__ lnb,
             ushort* __restrict__ Wfg) {
  const int L = threadIdx.x >> 6, co = threadIdx.x & 63;
  float bias = bs[L * 64 + co];
  float colsum = 0.f;
  ushort* row = Wfg + (size_t)(L * 64 + co) * 80;
  for (int ci = 0; ci < 64; ++ci) {
    const float w = Ws[((L * 64 + ci) << 6) + co];
    const float sc = (L > 0) ? lns[(L - 1) * 64 + ci] : 1.f;
    const float wp = sc * w;
    if (L > 0) bias += lnb[(L - 1) * 64 + ci] * w;
    colsum += wp;
    row[ci] = f2h(wp);
  }
  row[64] = f2h(bias);
  row[65] = f2h(colsum);
  for (int q = 66; q < 80; ++q) row[q] = 0;
}

// ---------------- K1: att (512 threads, k-split wave pairs) ----------------
template<bool F16OUT>
__global__ __launch_bounds__(512, 4)
void att_k1(const float* __restrict__ x, void* __restrict__ attout) {
  __shared__ __align__(16) ushort Mb[64 * 256];        // 32 KB  M[px][k] fp16
  __shared__ __align__(16) ushort Xb[64 * 256];        // 32 KB  X^T[ch][k] fp16
  __shared__ __align__(16) float  scr[4 * 4 * 64 * 4]; // 16 KB  [tile][reg4][lane]x4 partials
  const int tid = threadIdx.x;
  const int lane = tid & 63, w = tid >> 6;             // 8 waves
  const int l15 = lane & 15;
  const int l31 = lane & 31, lh = lane >> 5;
  const int ot = w & 3;                                // output tile 0..3
  const int pb = ot >> 1, cb2 = ot & 1;                // (px 32-block, ch 32-block)
  const int kh = w >> 2;                               // k-half 0/1

  // one-time zero of M (scatter slot-set is tile-invariant -> zeros persist)
  {
    const short8 z8 = {0,0,0,0,0,0,0,0};
    #pragma unroll
    for (int i = 0; i < 4; ++i)
      *reinterpret_cast<short8*>(&Mb[(tid + i * 512) * 8]) = z8;
  }

  const int b = blockIdx.x;
  const int tbase = (b & 7) * 1152 + (b >> 3) * 18;    // XCD-chunked tile bands
  // M-scatter ownership: pixel p = (w&3)*16+l15, 8 channels from (kh,lg)
  const int p  = (w & 3) * 16 + l15;
  const int pr = p >> 3, pc = p & 7;
  const int cb = ((kh << 2) + (lane >> 4 & 3)) << 3;   // channel base 0,8,...,56
  const int kr0 = pr + (cb >> 3);                      // M k-row for this thread's 8 ch

  // pipeline registers (2 halo rows per thread: r = w, w+8)
  float4 cv[2];
  float Rv[2][8];
  float Lv[2][8];
  short8 rs[2];

  // fast == tile interior: rows ti-3..ti+11 and cols tj-3..tj+12 all inside the image.
  auto issue_loads = [&](int ti, int tj, bool fresh, bool fast) {
    {
      const float* cp = x + ((size_t)((ti + pr) * WW + (tj + pc)) << 6) + cb;
      cv[0] = *reinterpret_cast<const float4*>(cp);
      cv[1] = *reinterpret_cast<const float4*>(cp + 4);
    }
    #pragma unroll
    for (int i = 0; i < 2; ++i) {
      const int r = w + 8 * i;
      if (r < 15) {
        if (fast) {
          const int gr = ti + r - 3;
          const float* rowp = x + ((size_t)(gr * WW + tj) << 6) + lane;
          #pragma unroll
          for (int s = 0; s < 8; ++s)
            Rv[i][s] = rowp[(5 + s) << 6];             // imm offsets
          if (fresh) {
            #pragma unroll
            for (int s = 0; s < 8; ++s)
              Lv[i][s] = rowp[(s - 3) << 6];
          }
        } else {
          const int gr = min(max(ti + r - 3, 0), HH - 1);
          const float* rowp = x + ((size_t)gr * WW << 6) + lane;
          #pragma unroll
          for (int s = 0; s < 8; ++s) {
            const int gc = min(max(tj + 5 + s, 0), WW - 1);
            Rv[i][s] = rowp[(size_t)gc << 6];
          }
          if (fresh) {
            #pragma unroll
            for (int s = 0; s < 8; ++s) {
              const int gc = min(max(tj - 3 + s, 0), WW - 1);
              Lv[i][s] = rowp[(size_t)gc << 6];
            }
          }
        }
      }
    }
  };

  auto write_lds = [&](int ti, int tj, bool fresh, bool fast) {
    // M scatter: sigmoid(center) fp16, 8 channels (center always in-bounds)
    #pragma unroll
    for (int qd = 0; qd < 2; ++qd) {
      const float vs[4] = {cv[qd].x, cv[qd].y, cv[qd].z, cv[qd].w};
      #pragma unroll
      for (int j = 0; j < 4; ++j) {
        const int k = (kr0 << 4) + pc + qd * 4 + j;
        Mb[eoff(p, k)] = f2h(sigmoidf(vs[j]));
      }
    }
    // X^T rows: left8 = reused old right (or fresh pack), right8 = new
    #pragma unroll
    for (int i = 0; i < 2; ++i) {
      const int r = w + 8 * i;
      if (r < 15) {
        short8 left8, right8;
        if (fast) {
          if (fresh) {
            #pragma unroll
            for (int s = 0; s < 8; ++s) left8[s] = (short)f2h(Lv[i][s]);
          } else {
            left8 = rs[i];
          }
          #pragma unroll
          for (int s = 0; s < 8; ++s) right8[s] = (short)f2h(Rv[i][s]);
        } else {
          const int gr = ti + r - 3;
          const bool rok = (unsigned)gr < (unsigned)HH;
          if (fresh) {
            #pragma unroll
            for (int s = 0; s < 8; ++s) {
              const int j = tj - 3 + s;
              const bool ok = rok && ((unsigned)j < (unsigned)WW);
              left8[s] = (short)f2h(ok ? Lv[i][s] : 0.f);
            }
          } else {
            left8 = rs[i];
          }
          #pragma unroll
          for (int s = 0; s < 8; ++s) {
            const int j = tj + 5 + s;
            const bool ok = rok && ((unsigned)j < (unsigned)WW);
            right8[s] = (short)f2h(ok ? Rv[i][s] : 0.f);
          }
        }
        *reinterpret_cast<short8*>(&Xb[goff(lane, 2 * r)])     = left8;
        *reinterpret_cast<short8*>(&Xb[goff(lane, 2 * r + 1)]) = right8;
        rs[i] = right8;
      }
    }
  };

  f32x16 acc;
  int pti = 0, ptj = 0;

  auto store_acc = [&](int ti, int tj) {   // kh==0 waves only
    #pragma unroll
    for (int reg = 0; reg < 16; ++reg) {
      const float v = acc[reg];
      const int prow = (reg & 3) + 8 * (reg >> 2) + 4 * lh;
      const int p2 = pb * 32 + prow;
      const size_t gpx = (size_t)(ti + (p2 >> 3)) * WW + (tj + (p2 & 7));
      const int ch = cb2 * 32 + l31;
      if (F16OUT) ((ushort*)attout)[(gpx << 6) + ch] = f2h(v);
      else        ((float*)attout)[(gpx << 6) + ch] = v;
    }
  };

  auto tile_fast = [](int ti, int tj, bool fresh) {
    return (ti != 0) && (ti != HH - 8) && (tj != WW - 8) && (!fresh || tj != 0);
  };

  {
    const int ti0 = (tbase / 96) * 8, tj0 = (tbase % 96) * 8;
    issue_loads(ti0, tj0, true, tile_fast(ti0, tj0, true));
  }

  for (int t18 = 0; t18 < 18; ++t18) {
    const int tile = tbase + t18;
    const int ti = (tile / 96) * 8, tj = (tile % 96) * 8;
    const bool fresh = (t18 == 0) || (tj == 0);

    __syncthreads();                       // S0: prev LDS reads done; kh=1 scr writes visible
    if (kh == 0 && t18 > 0) {              // fold tile t-1 kh=1 partials into acc
      #pragma unroll
      for (int q = 0; q < 4; ++q) {
        const float4 pv = *reinterpret_cast<const float4*>(&scr[ot * 1024 + q * 256 + lane * 4]);
        acc[q * 4 + 0] += pv.x; acc[q * 4 + 1] += pv.y;
        acc[q * 4 + 2] += pv.z; acc[q * 4 + 3] += pv.w;
      }
    }
    write_lds(ti, tj, fresh, tile_fast(ti, tj, fresh));
    __syncthreads();                       // S1: M + X visible
    if (kh == 0 && t18 > 0) store_acc(pti, ptj);
    if (t18 < 17) {
      const int nt = tile + 1;
      const int nti = (nt / 96) * 8, ntj = (nt % 96) * 8;
      const bool nfresh = (nt % 96) == 0;
      issue_loads(nti, ntj, nfresh, tile_fast(nti, ntj, nfresh));
    }

    // GEMM: this wave's k-half (kh=0: ks 0..6, kh=1: ks 7..14)
    acc = (f32x16){0,0,0,0,0,0,0,0,0,0,0,0,0,0,0,0};
    const int ks0 = kh ? 7 : 0, ks1 = kh ? 15 : 7;
    #pragma unroll 8
    for (int ks = ks0; ks < ks1; ++ks) {
      const int g = 2 * ks + lh;
      const half8 a  = *reinterpret_cast<const half8*>(&Mb[goff(pb * 32 + l31, g)]);
      const half8 bb = *reinterpret_cast<const half8*>(&Xb[goff(cb2 * 32 + l31, g)]);
      acc = __builtin_amdgcn_mfma_f32_32x32x16_f16(a, bb, acc, 0, 0, 0);
    }
    if (kh == 1) {                         // publish partial (read at next S0)
      #pragma unroll
      for (int q = 0; q < 4; ++q) {
        float4 pv;
        pv.x = acc[q * 4 + 0]; pv.y = acc[q * 4 + 1];
        pv.z = acc[q * 4 + 2]; pv.w = acc[q * 4 + 3];
        *reinterpret_cast<float4*>(&scr[ot * 1024 + q * 256 + lane * 4]) = pv;
      }
    }
    pti = ti; ptj = tj;
  }
  __syncthreads();                         // final: scr for tile 17 visible
  if (kh == 0) {
    #pragma unroll
    for (int q = 0; q < 4; ++q) {
      const float4 pv = *reinterpret_cast<const float4*>(&scr[ot * 1024 + q * 256 + lane * 4]);
      acc[q * 4 + 0] += pv.x; acc[q * 4 + 1] += pv.y;
      acc[q * 4 + 2] += pv.z; acc[q * 4 + 3] += pv.w;
    }
    store_acc(pti, ptj);
  }
}

// ---------------- K2: MLP + LN + head (unchanged from R11) ----------------
__device__ __forceinline__ float zsel(const f32x16& z0, const f32x16& z1, int nb, int idx) {
  return nb ? z1[idx] : z0[idx];
}

template<bool F16IN>
__global__ __launch_bounds__(512, 2)
void mlp_k2(const void* attv, const ushort* __restrict__ Wfg,
            const float* __restrict__ lns, const float* __restrict__ lnb,
            const float* __restrict__ w_out, const float* __restrict__ b_out,
            float* x0_out, float* __restrict__ out1) {
  __shared__ __align__(16) ushort wt[4 * 64 * 88];
  __shared__ __align__(16) ushort act[8][32 * 88];
  __shared__ __align__(16) ushort kpat[16];
  const int tid = threadIdx.x;
  const int lane = tid & 63, wid = tid >> 6;
  const int l31 = lane & 31, lh = lane >> 5;

  for (int idx = tid; idx < 4 * 64 * 10; idx += 512) {
    const int row = idx / 10, q = idx - row * 10;
    *reinterpret_cast<uint4*>(&wt[row * 88 + q * 8]) =
        *reinterpret_cast<const uint4*>(&Wfg[(size_t)row * 80 + q * 8]);
  }
  for (int idx = tid; idx < 256; idx += 512) {
    ushort* rp = &act[idx >> 5][(idx & 31) * 88];
    for (int q = 64; q < 88; ++q) rp[q] = 0;
    rp[64] = 0x3C00;
  }
  if (tid < 16) kpat[tid] = (tid == 0) ? (ushort)0x3C00 : (ushort)0;

  float sc3[2][4][4], lb3[2][4][4], wo3[2][4][4];
  #pragma unroll
  for (int nb = 0; nb < 2; ++nb)
    #pragma unroll
    for (int hi = 0; hi < 4; ++hi)
      #pragma unroll
      for (int j = 0; j < 4; ++j) {
        const int ch = nb * 32 + hi * 8 + lh * 4 + j;
        sc3[nb][hi][j] = lns[192 + ch];
        lb3[nb][hi][j] = lnb[192 + ch];
        wo3[nb][hi][j] = w_out[ch];
      }
  const float b0s = b_out[0];
  __syncthreads();

  ushort* const myact = act[wid];

  for (int it = 0; it < 9; ++it) {
    const int px = ((it * 256 + (int)blockIdx.x) * 8 + wid) * 32 + l31;

    half8 bfr[5];
    if (F16IN) {
      const ushort* ap = (const ushort*)attv + ((size_t)px << 6) + lh * 8;
      #pragma unroll
      for (int g = 0; g < 4; ++g)
        bfr[g] = *reinterpret_cast<const half8*>(ap + g * 16);
    } else {
      const float* ap = (const float*)attv + ((size_t)px << 6) + lh * 8;
      #pragma unroll
      for (int g = 0; g < 4; ++g) {
        const float4 fa = *reinterpret_cast<const float4*>(ap + g * 16);
        const float4 fb = *reinterpret_cast<const float4*>(ap + g * 16 + 4);
        half8 h;
        h[0]=(_Float16)fa.x; h[1]=(_Float16)fa.y; h[2]=(_Float16)fa.z; h[3]=(_Float16)fa.w;
        h[4]=(_Float16)fb.x; h[5]=(_Float16)fb.y; h[6]=(_Float16)fb.z; h[7]=(_Float16)fb.w;
        bfr[g] = h;
      }
    }
    bfr[4] = *reinterpret_cast<const half8*>(&kpat[lh * 8]);

    f32x16 z0, z1;
    float mu = 0.f, rstd = 1.f;
    #pragma unroll
    for (int L = 0; L < 4; ++L) {
      if (L > 0) {
        #pragma unroll
        for (int g = 0; g < 5; ++g)
          bfr[g] = *reinterpret_cast<const half8*>(&myact[l31 * 88 + g * 16 + lh * 8]);
      }
      z0 = (f32x16){0,0,0,0,0,0,0,0,0,0,0,0,0,0,0,0};
      z1 = (f32x16){0,0,0,0,0,0,0,0,0,0,0,0,0,0,0,0};
      #pragma unroll
      for (int g = 0; g < 5; ++g) {
        const half8 a0 = *reinterpret_cast<const half8*>(&wt[(L * 64      + l31) * 88 + g * 16 + lh * 8]);
        const half8 a1 = *reinterpret_cast<const half8*>(&wt[(L * 64 + 32 + l31) * 88 + g * 16 + lh * 8]);
        z0 = __builtin_amdgcn_mfma_f32_32x32x16_f16(a0, bfr[g], z0, 0, 0, 0);
        z1 = __builtin_amdgcn_mfma_f32_32x32x16_f16(a1, bfr[g], z1, 0, 0, 0);
      }
      float sp[4] = {0.f, 0.f, 0.f, 0.f}, qp[4] = {0.f, 0.f, 0.f, 0.f};
      #pragma unroll
      for (int r = 0; r < 16; ++r) {
        const float v0 = fmaxf(z0[r], 0.f); z0[r] = v0;
        const float v1 = fmaxf(z1[r], 0.f); z1[r] = v1;
        sp[r & 3] += v0 + v1;
        qp[r & 3] += v0 * v0 + v1 * v1;
      }
      float s = (sp[0] + sp[1]) + (sp[2] + sp[3]);
      float qq = (qp[0] + qp[1]) + (qp[2] + qp[3]);
      s  += __shfl_xor(s, 32, 64);
      qq += __shfl_xor(qq, 32, 64);
      mu = s * 0.015625f;
      const float var = qq * 0.015625f - mu * mu;
      rstd = rsqrtf(var + 1e-6f);
      if (L < 3) {
        #pragma unroll
        for (int nb = 0; nb < 2; ++nb)
          #pragma unroll
          for (int hi = 0; hi < 4; ++hi) {
            ushort4 pk;
            pk.x = f2h(rstd * zsel(z0, z1, nb, hi * 4 + 0));
            pk.y = f2h(rstd * zsel(z0, z1, nb, hi * 4 + 1));
            pk.z = f2h(rstd * zsel(z0, z1, nb, hi * 4 + 2));
            pk.w = f2h(rstd * zsel(z0, z1, nb, hi * 4 + 3));
            *reinterpret_cast<ushort4*>(&myact[l31 * 88 + nb * 32 + hi * 8 + lh * 4]) = pk;
          }
        if (lh == 0) myact[l31 * 88 + 65] = f2h(-(mu * rstd));
      }
    }

    const float t = mu * rstd;
    float part0 = 0.f, part1 = 0.f;
    #pragma unroll
    for (int nb = 0; nb < 2; ++nb)
      #pragma unroll
      for (int hi = 0; hi < 4; ++hi) {
        f32x4 yv;
        #pragma unroll
        for (int j = 0; j < 4; ++j) {
          const float v = zsel(z0, z1, nb, hi * 4 + j);
          const float y = v * (rstd * sc3[nb][hi][j]) + (lb3[nb][hi][j] - t * sc3[nb][hi][j]);
          yv[j] = y;
          if (j & 1) part1 += y * wo3[nb][hi][j];
          else       part0 += y * wo3[nb][hi][j];
        }
        *reinterpret_cast<f32x4*>(&x0_out[((size_t)px << 6) + nb * 32 + hi * 8 + lh * 4]) = yv;
      }
    float part = part0 + part1;
    part += __shfl_xor(part, 32, 64);
    if (lh == 0) out1[px] = part + b0s;
  }
}

extern "C" void kernel_launch(void* const* d_in, const int* in_sizes, int n_in,
                              void* d_out, int out_size, void* d_ws, size_t ws_size,
                              hipStream_t stream) {
  const float* x     = (const float*)d_in[0];
  const float* Ws    = (const float*)d_in[1];
  const float* bs    = (const float*)d_in[2];
  const float* lns   = (const float*)d_in[3];
  const float* lnbv  = (const float*)d_in[4];
  const float* w_out = (const float*)d_in[5];
  const float* b_out = (const float*)d_in[6];
  float* x0_out = (float*)d_out;
  float* out1   = x0_out + (size_t)HWPX * 64;

  const size_t attBytes = (size_t)HWPX * 64 * sizeof(ushort);   // 75.5 MB
  if (ws_size >= attBytes + 65536) {
    ushort* atth = (ushort*)d_ws;
    ushort* Wfg  = (ushort*)((char*)d_ws + attBytes);
    prep_wf<<<1, 256, 0, stream>>>(Ws, bs, lns, lnbv, Wfg);
    att_k1<true><<<512, 512, 0, stream>>>(x, atth);
    mlp_k2<true><<<256, 512, 0, stream>>>(atth, Wfg, lns, lnbv,
                                          w_out, b_out, x0_out, out1);
  } else {
    ushort* Wfg = (ushort*)d_ws;
    prep_wf<<<1, 256, 0, stream>>>(Ws, bs, lns, lnbv, Wfg);
    att_k1<false><<<512, 512, 0, stream>>>(x, d_out);
    mlp_k2<false><<<256, 512, 0, stream>>>(d_out, Wfg, lns, lnbv,
                                           w_out, b_out, x0_out, out1);
  }
}